// Round 11
// baseline (1525.342 us; speedup 1.0000x reference)
//
#include <hip/hip_runtime.h>
#include <hip/hip_bf16.h>
#include <math.h>

#define N_NODES 20000
#define N_EDGES 640000
#define CH 256        // HEADS*DIM
#define LAYERS 4
#define HID 512
#define G4 2048       // 4*HID
#define EPS 1e-5f
#define SLOPE 0.2f

typedef __bf16 bf16x8 __attribute__((ext_vector_type(8)));
typedef float  f32x4  __attribute__((ext_vector_type(4)));

// ---------------- helpers ----------------
// async global->LDS, 16B per lane; lds dest = wave-uniform base + lane*16
__device__ __forceinline__ void gload16(const void* g, void* l){
  __builtin_amdgcn_global_load_lds(
      (const __attribute__((address_space(1))) void*)g,
      (__attribute__((address_space(3))) void*)l, 16, 0, 0);
}

// bf16 pair -> float2 (bf16->f32 is a 16-bit shift)
__device__ __forceinline__ float2 ldbf2(const __hip_bfloat16* p){
  unsigned u = *(const unsigned*)p;
  float2 r;
  r.x = __uint_as_float(u << 16);
  r.y = __uint_as_float(u & 0xffff0000u);
  return r;
}

// fast tanh: 1 - 2/(e^{2x}+1); saturates to +/-1 (e=inf -> 1, e=0 -> -1), no NaN
__device__ __forceinline__ float fast_tanh(float x){
  float e = __expf(2.f * x);
  return 1.f - 2.f / (e + 1.f);
}

// bijective chunked XCD swizzle (m204): contiguous wgid ranges per XCD
__device__ __forceinline__ int xcd_swz(int orig, int q, int r){
  int xcd = orig & 7, idx = orig >> 3;
  return (xcd < r ? xcd * (q + 1) : r * (q + 1) + (xcd - r) * q) + idx;
}

// ---------------- CSR build ----------------
__global__ void k_hist(const int* __restrict__ dst, int* __restrict__ cnt){
  int e = blockIdx.x * 256 + threadIdx.x;
  if (e < N_EDGES) atomicAdd(&cnt[dst[e]], 1);
}

__global__ __launch_bounds__(1024) void k_scan(const int* __restrict__ cnt,
                                               int* __restrict__ indptr,
                                               int* __restrict__ cursor){
  __shared__ int buf[1024];
  __shared__ int carry;
  if (threadIdx.x == 0) carry = 0;
  __syncthreads();
  for (int base = 0; base < N_NODES; base += 1024){
    int i = base + threadIdx.x;
    int v = (i < N_NODES) ? cnt[i] : 0;
    buf[threadIdx.x] = v;
    __syncthreads();
#pragma unroll
    for (int off = 1; off < 1024; off <<= 1){
      int t = (threadIdx.x >= off) ? buf[threadIdx.x - off] : 0;
      __syncthreads();
      buf[threadIdx.x] += t;
      __syncthreads();
    }
    int excl = buf[threadIdx.x] - v;
    if (i < N_NODES){
      indptr[i] = carry + excl;
      cursor[i] = carry + excl;
    }
    __syncthreads();
    if (threadIdx.x == 0) carry += buf[1023];
    __syncthreads();
  }
  if (threadIdx.x == 0) indptr[N_NODES] = carry;
}

// scatter src + edge_attr into dst-sorted order
__global__ void k_scatter(const int* __restrict__ src, const int* __restrict__ dst,
                          const float* __restrict__ ea, int* __restrict__ cursor,
                          int* __restrict__ esrc, float* __restrict__ eea){
  int e = blockIdx.x * 256 + threadIdx.x;
  if (e < N_EDGES){
    int pos = atomicAdd(&cursor[dst[e]], 1);
    esrc[pos] = src[e];
    eea[pos] = ea[e];
  }
}

// ---------------- LSTM weight permute+convert ----------------
// in row r = g*512 + j  ->  out row nr = (j/16)*64 + g*16 + (j%16)
__global__ void k_wperm(const float* __restrict__ W, __hip_bfloat16* __restrict__ Wp,
                        int K){
  int idx = blockIdx.x * 256 + threadIdx.x;
  if (idx >= G4 * K) return;
  int r = idx / K, k = idx - r * K;
  int g = r >> 9, j = r & 511;
  int nr = ((j >> 4) << 6) + (g << 4) + (j & 15);
  Wp[(size_t)nr * K + k] = __float2bfloat16(W[idx]);
}

__global__ void k_bperm(const float* __restrict__ bih, const float* __restrict__ bhh,
                        float* __restrict__ bp){
  int r = blockIdx.x * 256 + threadIdx.x;   // 0..2047
  if (r >= G4) return;
  int g = r >> 9, j = r & 511;
  int nr = ((j >> 4) << 6) + (g << 4) + (j & 15);
  bp[nr] = bih[r] + bhh[r];
}

// GAT weight transpose+convert: Wl,Wr [K=256][N=256] k-major f32 ->
// out [512][256] n-major bf16 (rows 0-255 = Wl^T, 256-511 = Wr^T)
__global__ void k_wtrans(const float* __restrict__ Wl, const float* __restrict__ Wr,
                         __hip_bfloat16* __restrict__ out){
  int idx = blockIdx.x * 256 + threadIdx.x;
  if (idx >= CH * CH) return;
  int n = idx >> 8, k = idx & 255;
  out[(size_t)n * CH + k]        = __float2bfloat16(Wl[(size_t)k * CH + n]);
  out[(size_t)(CH + n) * CH + k] = __float2bfloat16(Wr[(size_t)k * CH + n]);
}

// ---------------- layer-0 transform (K=2): xl -> bf16, xr -> f32 ----------------
__global__ void k_xf0(const float* __restrict__ x, const float* __restrict__ Wl,
                      const float* __restrict__ Wr, __hip_bfloat16* __restrict__ xlb,
                      float* __restrict__ xr){
  int idx = blockIdx.x * 256 + threadIdx.x;
  int n = idx >> 8, cx = idx & 255;
  float x0 = x[n * 2], x1 = x[n * 2 + 1];
  xlb[idx] = __float2bfloat16(fmaf(x0, Wl[cx], x1 * Wl[CH + cx]));
  xr[idx]  = fmaf(x0, Wr[cx], x1 * Wr[CH + cx]);
}

// ---------------- fused GAT transform (MFMA): [xl|xr] = xs_prev * [Wl|Wr] ----------------
// A:[M][256] bf16, B:[512][256] bf16 n-major. cols 0-255 -> xlb bf16, 256-511 -> xr f32.
__global__ __launch_bounds__(256) void k_xform(
    const __hip_bfloat16* __restrict__ A, const __hip_bfloat16* __restrict__ B,
    __hip_bfloat16* __restrict__ xlb, float* __restrict__ xr, int M)
{
  __shared__ __align__(16) unsigned short As[128 * 32];
  __shared__ __align__(16) unsigned short Bs[128 * 32];
  const int wgid = xcd_swz(blockIdx.x, 628 >> 3, 628 & 7);
  const int m0 = (wgid >> 2) * 128, n0 = (wgid & 3) * 128;   // m-major: A-panel reuse
  const int tid = threadIdx.x;
  const int lane = tid & 63, w = tid >> 6;
  const int wr = w >> 1, wc = w & 1;
  const int l15 = lane & 15, l4 = lane >> 4;
  const int srow = lane >> 2;
  const int skk  = (lane & 3) * 8;

  f32x4 acc[4][4];
#pragma unroll
  for (int i = 0; i < 4; i++)
#pragma unroll
    for (int j = 0; j < 4; j++) acc[i][j] = (f32x4){0.f, 0.f, 0.f, 0.f};

  for (int kt = 0; kt < 8; ++kt){
    int k0 = kt * 32;
#pragma unroll
    for (int i = 0; i < 2; i++){
      int rbase = w * 32 + i * 16;
      int row = rbase + srow;
      gload16(A + (size_t)(m0 + row) * CH + k0 + skk, &As[rbase * 32]);
      gload16(B + (size_t)(n0 + row) * CH + k0 + skk, &Bs[rbase * 32]);
    }
    __syncthreads();
    bf16x8 af[4], bfr[4];
#pragma unroll
    for (int f = 0; f < 4; f++){
      af[f]  = *(const bf16x8*)&As[(wr * 64 + f * 16 + l15) * 32 + l4 * 8];
      bfr[f] = *(const bf16x8*)&Bs[(wc * 64 + f * 16 + l15) * 32 + l4 * 8];
    }
#pragma unroll
    for (int fi = 0; fi < 4; fi++)
#pragma unroll
      for (int fj = 0; fj < 4; fj++)
        acc[fi][fj] = __builtin_amdgcn_mfma_f32_16x16x32_bf16(af[fi], bfr[fj],
                                                              acc[fi][fj], 0, 0, 0);
    __syncthreads();
  }

  // epilogue: D col = lane&15, row = (lane>>4)*4 + reg [m89]; split outputs at col 256
#pragma unroll
  for (int fj = 0; fj < 4; fj++){
    int col = n0 + wc * 64 + fj * 16 + l15;
#pragma unroll
    for (int fi = 0; fi < 4; fi++){
      int rbase = m0 + wr * 64 + fi * 16 + l4 * 4;
#pragma unroll
      for (int r = 0; r < 4; r++){
        int row = rbase + r;
        if (row < M){
          if (col < CH) xlb[(size_t)row * CH + col] = __float2bfloat16(acc[fi][fj][r]);
          else          xr[(size_t)row * CH + (col - CH)] = acc[fi][fj][r];
        }
      }
    }
  }
}

// ---------------- fused LSTM step: gates GEMM + cell + JK partial ----------------
// 1-D grid 2512 with XCD swizzle, m-major (16 y-blocks of a panel share an XCD L2).
// A1:[M][256] bf16 (xs_t), A2:[M][512] bf16 (h_in, K2=0 at t=0)
// B1/B2: PERMUTED weights [2048][K] bf16; biasp: permuted bih+bhh [2048] f32
// h_out MUST differ from h_in (A2 rows are read by all y-blocks of the panel).
__global__ __launch_bounds__(256) void k_lstm_step(
    const __hip_bfloat16* __restrict__ A1, int K1,
    const __hip_bfloat16* __restrict__ A2, int K2,
    const __hip_bfloat16* __restrict__ B1, const __hip_bfloat16* __restrict__ B2,
    const float* __restrict__ biasp, __hip_bfloat16* __restrict__ h_out,
    float* __restrict__ c, const float* __restrict__ jkw,
    float* __restrict__ score, int M, int first)
{
  __shared__ __align__(16) unsigned short As[128 * 32];
  __shared__ __align__(16) unsigned short Bs[128 * 32];
  const int wgid = xcd_swz(blockIdx.x, 2512 >> 3, 2512 & 7);
  const int m0 = (wgid >> 4) * 128;
  const int yb = wgid & 15;
  const int n0 = yb * 128;
  const int tid = threadIdx.x;
  const int lane = tid & 63, w = tid >> 6;
  const int wr = w >> 1, wc = w & 1;
  const int l15 = lane & 15, l4 = lane >> 4;
  const int srow = lane >> 2;
  const int skk  = (lane & 3) * 8;

  f32x4 acc[4][4];
#pragma unroll
  for (int i = 0; i < 4; i++)
#pragma unroll
    for (int j = 0; j < 4; j++) acc[i][j] = (f32x4){0.f, 0.f, 0.f, 0.f};

  const int nt1 = K1 / 32, nt2 = K2 / 32;

  for (int kt = 0; kt < nt1 + nt2; ++kt){
    const __hip_bfloat16* Ab; const __hip_bfloat16* Bb; int K, k0;
    if (kt < nt1){ Ab = A1; Bb = B1; K = K1; k0 = kt * 32; }
    else         { Ab = A2; Bb = B2; K = K2; k0 = (kt - nt1) * 32; }
#pragma unroll
    for (int i = 0; i < 2; i++){
      int rbase = w * 32 + i * 16;
      int row = rbase + srow;
      gload16(Ab + (size_t)(m0 + row) * K + k0 + skk, &As[rbase * 32]);
      gload16(Bb + (size_t)(n0 + row) * K + k0 + skk, &Bs[rbase * 32]);
    }
    __syncthreads();
    bf16x8 af[4], bfr[4];
#pragma unroll
    for (int f = 0; f < 4; f++){
      af[f]  = *(const bf16x8*)&As[(wr * 64 + f * 16 + l15) * 32 + l4 * 8];
      bfr[f] = *(const bf16x8*)&Bs[(wc * 64 + f * 16 + l15) * 32 + l4 * 8];
    }
#pragma unroll
    for (int fi = 0; fi < 4; fi++)
#pragma unroll
      for (int fj = 0; fj < 4; fj++)
        acc[fi][fj] = __builtin_amdgcn_mfma_f32_16x16x32_bf16(af[fi], bfr[fj],
                                                              acc[fi][fj], 0, 0, 0);
    __syncthreads();
  }

  // ---- fused cell epilogue ----
  const int block64 = yb * 2 + wc;             // 0..31
  const int j = block64 * 16 + l15;            // hidden channel 0..511
  const float bi0 = biasp[block64 * 64 + l15];
  const float bi1 = biasp[block64 * 64 + 16 + l15];
  const float bi2 = biasp[block64 * 64 + 32 + l15];
  const float bi3 = biasp[block64 * 64 + 48 + l15];
  const float jw  = jkw[j];
#pragma unroll
  for (int fi = 0; fi < 4; fi++){
#pragma unroll
    for (int r = 0; r < 4; r++){
      int node = m0 + wr * 64 + fi * 16 + l4 * 4 + r;
      float p = 0.f;
      if (node < M){
        float gi = acc[fi][0][r] + bi0;
        float gf = acc[fi][1][r] + bi1;
        float gg = acc[fi][2][r] + bi2;
        float go = acc[fi][3][r] + bi3;
        size_t hb = (size_t)node * HID + j;
        float cv = first ? 0.f : c[hb];
        float iv = 1.f / (1.f + __expf(-gi));
        float fv = 1.f / (1.f + __expf(-gf));
        float ov = 1.f / (1.f + __expf(-go));
        float cn = fv * cv + iv * fast_tanh(gg);
        float hn = ov * fast_tanh(cn);
        c[hb] = cn;
        h_out[hb] = __float2bfloat16(hn);
        p = hn * jw;
      }
      p += __shfl_xor(p, 1, 64); p += __shfl_xor(p, 2, 64);
      p += __shfl_xor(p, 4, 64); p += __shfl_xor(p, 8, 64);
      if (l15 == 0 && node < M) atomicAdd(&score[node], p);
    }
  }
}

// ---------------- fused GAT message pass (bf16 gathers, 4-way unrolled) ----------------
__global__ __launch_bounds__(128) void k_gat(
    const int* __restrict__ indptr, const int* __restrict__ esrc,
    const float* __restrict__ eea, const __hip_bfloat16* __restrict__ xlb,
    const float* __restrict__ xr, const float* __restrict__ We,
    const float* __restrict__ att, const float* __restrict__ bias,
    __hip_bfloat16* __restrict__ xsb)
{
  const int n = blockIdx.x;
  const int t = threadIdx.x;              // ch pair (2t, 2t+1); head = t>>5
  const int c0 = 2 * t;
  const int s0 = indptr[n], s1 = indptr[n + 1];
  const float2 xr_t = *(const float2*)&xr[(size_t)n * CH + c0];
  const float2 We_t = *(const float2*)&We[c0];
  const float2 at_t = *(const float2*)&att[c0];
  float m = -1e30f, l = 0.f;
  float2 acc = make_float2(0.f, 0.f);

  int i = s0;
  for (; i + 3 < s1; i += 4){             // 4-way unroll: 4 gathers in flight
    int   sA = esrc[i],     sB = esrc[i + 1];
    int   sC = esrc[i + 2], sD = esrc[i + 3];
    float aA = eea[i],      aB = eea[i + 1];
    float aC = eea[i + 2],  aD = eea[i + 3];
    float2 xvA = ldbf2(xlb + (size_t)sA * CH + c0);
    float2 xvB = ldbf2(xlb + (size_t)sB * CH + c0);
    float2 xvC = ldbf2(xlb + (size_t)sC * CH + c0);
    float2 xvD = ldbf2(xlb + (size_t)sD * CH + c0);
    // pre-activation + leaky-relu + att-dot (independent per edge)
    float vxA = xvA.x + xr_t.x + aA * We_t.x, vyA = xvA.y + xr_t.y + aA * We_t.y;
    float vxB = xvB.x + xr_t.x + aB * We_t.x, vyB = xvB.y + xr_t.y + aB * We_t.y;
    float vxC = xvC.x + xr_t.x + aC * We_t.x, vyC = xvC.y + xr_t.y + aC * We_t.y;
    float vxD = xvD.x + xr_t.x + aD * We_t.x, vyD = xvD.y + xr_t.y + aD * We_t.y;
    vxA = vxA > 0.f ? vxA : SLOPE * vxA;  vyA = vyA > 0.f ? vyA : SLOPE * vyA;
    vxB = vxB > 0.f ? vxB : SLOPE * vxB;  vyB = vyB > 0.f ? vyB : SLOPE * vyB;
    vxC = vxC > 0.f ? vxC : SLOPE * vxC;  vyC = vyC > 0.f ? vyC : SLOPE * vyC;
    vxD = vxD > 0.f ? vxD : SLOPE * vxD;  vyD = vyD > 0.f ? vyD : SLOPE * vyD;
    float pA = vxA * at_t.x + vyA * at_t.y;
    float pB = vxB * at_t.x + vyB * at_t.y;
    float pC = vxC * at_t.x + vyC * at_t.y;
    float pD = vxD * at_t.x + vyD * at_t.y;
    // 4 independent 32-lane reduce chains (compiler interleaves)
#pragma unroll
    for (int off = 16; off; off >>= 1){
      pA += __shfl_xor(pA, off, 64);
      pB += __shfl_xor(pB, off, 64);
      pC += __shfl_xor(pC, off, 64);
      pD += __shfl_xor(pD, off, 64);
    }
    // sequential online-softmax updates (same FP order as 1-at-a-time)
    float mn = fmaxf(m, pA);
    float sc = __expf(m - mn), wE = __expf(pA - mn);
    l = l * sc + wE;
    acc.x = acc.x * sc + wE * xvA.x;  acc.y = acc.y * sc + wE * xvA.y;
    m = mn;
    mn = fmaxf(m, pB);
    sc = __expf(m - mn); wE = __expf(pB - mn);
    l = l * sc + wE;
    acc.x = acc.x * sc + wE * xvB.x;  acc.y = acc.y * sc + wE * xvB.y;
    m = mn;
    mn = fmaxf(m, pC);
    sc = __expf(m - mn); wE = __expf(pC - mn);
    l = l * sc + wE;
    acc.x = acc.x * sc + wE * xvC.x;  acc.y = acc.y * sc + wE * xvC.y;
    m = mn;
    mn = fmaxf(m, pD);
    sc = __expf(m - mn); wE = __expf(pD - mn);
    l = l * sc + wE;
    acc.x = acc.x * sc + wE * xvD.x;  acc.y = acc.y * sc + wE * xvD.y;
    m = mn;
  }
  for (; i < s1; ++i){                    // remainder (<=3 edges)
    int   sA = esrc[i];
    float aA = eea[i];
    float2 xvA = ldbf2(xlb + (size_t)sA * CH + c0);
    float vx = xvA.x + xr_t.x + aA * We_t.x;
    float vy = xvA.y + xr_t.y + aA * We_t.y;
    vx = vx > 0.f ? vx : SLOPE * vx;
    vy = vy > 0.f ? vy : SLOPE * vy;
    float pl = vx * at_t.x + vy * at_t.y;
#pragma unroll
    for (int off = 16; off; off >>= 1) pl += __shfl_xor(pl, off, 64);
    float mn = fmaxf(m, pl);
    float sc = __expf(m - mn), wA = __expf(pl - mn);
    l = l * sc + wA;
    acc.x = acc.x * sc + wA * xvA.x;
    acc.y = acc.y * sc + wA * xvA.y;
    m = mn;
  }
  float invl = (l > 0.f) ? 1.f / l : 0.f;
  float2 bia = *(const float2*)&bias[c0];
  float ox = acc.x * invl + bia.x;
  float oy = acc.y * invl + bia.y;
  ox = ox > 0.f ? ox : 0.f;
  oy = oy > 0.f ? oy : 0.f;
  ushort2 hp;
  hp.x = __bfloat16_as_ushort(__float2bfloat16(ox));
  hp.y = __bfloat16_as_ushort(__float2bfloat16(oy));
  *(ushort2*)&xsb[(size_t)n * CH + c0] = hp;
}

// ---------------- JK softmax combine + BN reduction (fused) ----------------
__global__ __launch_bounds__(256) void k_jk(const float* __restrict__ scores,
                                            const __hip_bfloat16* __restrict__ xsb,
                                            float* __restrict__ out,
                                            float* __restrict__ sums)
{
  const int cx = threadIdx.x;
  const size_t NC = (size_t)N_NODES * CH;
  float s = 0.f, s2 = 0.f;
  for (int n = blockIdx.x; n < N_NODES; n += gridDim.x){
    float s0 = scores[n], s1 = scores[N_NODES + n];
    float sc2 = scores[2 * N_NODES + n], s3 = scores[3 * N_NODES + n];
    float mx = fmaxf(fmaxf(s0, s1), fmaxf(sc2, s3));
    float e0 = __expf(s0 - mx), e1 = __expf(s1 - mx);
    float e2 = __expf(sc2 - mx), e3 = __expf(s3 - mx);
    float inv = 1.f / (e0 + e1 + e2 + e3);
    size_t idx = (size_t)n * CH + cx;
    float v = e0 * __bfloat162float(xsb[idx]) + e1 * __bfloat162float(xsb[NC + idx]) +
              e2 * __bfloat162float(xsb[2 * NC + idx]) +
              e3 * __bfloat162float(xsb[3 * NC + idx]);
    v *= inv;
    out[idx] = v;
    s += v;
    s2 = fmaf(v, v, s2);
  }
  atomicAdd(&sums[cx], s);
  atomicAdd(&sums[CH + cx], s2);
}

__global__ __launch_bounds__(256) void k_bnapply(float* __restrict__ out,
                                                 const float* __restrict__ sums,
                                                 const float* __restrict__ gamma,
                                                 const float* __restrict__ beta)
{
  int idx = blockIdx.x * 256 + threadIdx.x;
  int cx = idx & 255;
  const float invN = 1.f / (float)N_NODES;
  float mean = sums[cx] * invN;
  float var = sums[CH + cx] * invN - mean * mean;
  out[idx] = (out[idx] - mean) * rsqrtf(var + EPS) * gamma[cx] + beta[cx];
}

// ---------------- host ----------------
extern "C" void kernel_launch(void* const* d_in, const int* in_sizes, int n_in,
                              void* d_out, int out_size, void* d_ws, size_t ws_size,
                              hipStream_t stream)
{
  const float* x     = (const float*)d_in[0];
  const int*   eidx  = (const int*)d_in[1];
  const int*   srcp  = eidx;
  const int*   dstp  = eidx + N_EDGES;
  const float* ea    = (const float*)d_in[2];
  const float* Wl0   = (const float*)d_in[3];
  const float* Wr0   = (const float*)d_in[4];
  const float* We0   = (const float*)d_in[5];
  const float* att0  = (const float*)d_in[6];
  const float* b0    = (const float*)d_in[7];
  const float* WlR   = (const float*)d_in[8];
  const float* WrR   = (const float*)d_in[9];
  const float* WeR   = (const float*)d_in[10];
  const float* attR  = (const float*)d_in[11];
  const float* bR    = (const float*)d_in[12];
  const float* Wih_f = (const float*)d_in[13];
  const float* Whh_f = (const float*)d_in[14];
  const float* bih_f = (const float*)d_in[15];
  const float* bhh_f = (const float*)d_in[16];
  const float* Wih_b = (const float*)d_in[17];
  const float* Whh_b = (const float*)d_in[18];
  const float* bih_b = (const float*)d_in[19];
  const float* bhh_b = (const float*)d_in[20];
  const float* jkw   = (const float*)d_in[21];
  const float* gamma = (const float*)d_in[23];
  const float* beta  = (const float*)d_in[24];

  // ---------- byte-precise workspace layout ----------
  char* base = (char*)d_ws;
  const size_t NC   = (size_t)N_NODES * CH;          // 5,120,000 elems
  const size_t NH   = (size_t)N_NODES * HID;         // 10,240,000 elems
  size_t off = 0;
  __hip_bfloat16* wihf_p = (__hip_bfloat16*)(base + off); off += (size_t)G4 * CH * 2;
  __hip_bfloat16* whhf_p = (__hip_bfloat16*)(base + off); off += (size_t)G4 * HID * 2;
  __hip_bfloat16* wihb_p = (__hip_bfloat16*)(base + off); off += (size_t)G4 * CH * 2;
  __hip_bfloat16* whhb_p = (__hip_bfloat16*)(base + off); off += (size_t)G4 * HID * 2;
  float* biasf_p = (float*)(base + off); off += G4 * 4;
  float* biasb_p = (float*)(base + off); off += G4 * 4;
  float* scores  = (float*)(base + off); off += (size_t)LAYERS * N_NODES * 4;
  float* sums    = (float*)(base + off); off += 2048;
  __hip_bfloat16* xsb = (__hip_bfloat16*)(base + off); off += LAYERS * NC * 2;
  const size_t R = off;                              // shared region base (~47.6 MB)
  // GAT view of R (all dead before LSTM phase)
  float* xr = (float*)(base + R);                    // [N][CH] f32 target transform
  __hip_bfloat16* xlb = (__hip_bfloat16*)(xr + NC);  // [N][CH] bf16 source transform
  int*   indptr = (int*)(xlb + NC);                  // N+1
  int*   cursor = indptr + (N_NODES + 1);            // N
  int*   esrc   = cursor + N_NODES;                  // E (dst-sorted src)
  float* eea    = (float*)(esrc + N_EDGES);          // E (dst-sorted edge_attr)
  __hip_bfloat16* wgat_p = (__hip_bfloat16*)(eea + N_EDGES);  // [3][512][256] bf16
  const size_t gat_end = R + NC * 4 + NC * 2
                       + (2 * (size_t)N_NODES + 1 + 2 * (size_t)N_EDGES) * 4
                       + 3 * (size_t)2 * CH * CH * 2;
  // LSTM view of R: h0, h1, c ordered so tail OOB reads stay interior
  __hip_bfloat16* hbuf0 = (__hip_bfloat16*)(base + R);            // [N][HID] bf16
  __hip_bfloat16* hbuf1 = (__hip_bfloat16*)(base + R + NH * 2);   // [N][HID] bf16
  float* cbuf  = (float*)(base + R + NH * 4);                     // [N][HID] f32
  const size_t lstm_end = R + NH * 4 + NH * 4;

  if (gat_end > ws_size || lstm_end > ws_size) return;  // leave output poisoned

  // ---- CSR by dst (src/ea stored dst-sorted) ----
  hipMemsetAsync(cursor, 0, N_NODES * sizeof(int), stream);
  k_hist<<<(N_EDGES + 255) / 256, 256, 0, stream>>>(dstp, cursor);
  k_scan<<<1, 1024, 0, stream>>>(cursor, indptr, cursor);
  k_scatter<<<(N_EDGES + 255) / 256, 256, 0, stream>>>(srcp, dstp, ea, cursor,
                                                       esrc, eea);

  // ---- weight prep ----
  k_wperm<<<(G4 * CH + 255) / 256, 256, 0, stream>>>(Wih_f, wihf_p, CH);
  k_wperm<<<(G4 * HID + 255) / 256, 256, 0, stream>>>(Whh_f, whhf_p, HID);
  k_wperm<<<(G4 * CH + 255) / 256, 256, 0, stream>>>(Wih_b, wihb_p, CH);
  k_wperm<<<(G4 * HID + 255) / 256, 256, 0, stream>>>(Whh_b, whhb_p, HID);
  k_bperm<<<(G4 + 255) / 256, 256, 0, stream>>>(bih_f, bhh_f, biasf_p);
  k_bperm<<<(G4 + 255) / 256, 256, 0, stream>>>(bih_b, bhh_b, biasb_p);
  for (int l = 0; l < LAYERS - 1; ++l)
    k_wtrans<<<(CH * CH + 255) / 256, 256, 0, stream>>>(
        WlR + (size_t)l * CH * CH, WrR + (size_t)l * CH * CH,
        wgat_p + (size_t)l * 2 * CH * CH);

  // ---- GATv2 layers (MFMA transforms from bf16 xs; fused message pass) ----
  for (int l = 0; l < LAYERS; ++l){
    if (l == 0){
      k_xf0<<<(int)(NC / 256), 256, 0, stream>>>(x, Wl0, Wr0, xlb, xr);
    } else {
      k_xform<<<628, 256, 0, stream>>>(
          xsb + (size_t)(l - 1) * NC, wgat_p + (size_t)(l - 1) * 2 * CH * CH,
          xlb, xr, N_NODES);
    }
    const float* We  = (l == 0) ? We0  : WeR  + (size_t)(l - 1) * CH;
    const float* att = (l == 0) ? att0 : attR + (size_t)(l - 1) * CH;
    const float* bia = (l == 0) ? b0   : bR   + (size_t)(l - 1) * CH;
    k_gat<<<N_NODES, 128, 0, stream>>>(indptr, esrc, eea, xlb, xr, We, att, bia,
                                       xsb + (size_t)l * NC);
  }

  // ---- LSTM (scores accumulated atomically; zero once) ----
  __hip_bfloat16* hb[2] = {hbuf0, hbuf1};
  hipMemsetAsync(scores, 0, (size_t)LAYERS * N_NODES * 4, stream);
  for (int t = 0; t < LAYERS; t++){
    k_lstm_step<<<2512, 256, 0, stream>>>(
        xsb + (size_t)t * NC, CH, hb[(t + 1) & 1], (t == 0) ? 0 : HID,
        wihf_p, whhf_p, biasf_p, hb[t & 1], cbuf, jkw,
        scores + (size_t)t * N_NODES, N_NODES, t == 0);
  }
  for (int s = 0; s < LAYERS; s++){
    int t = LAYERS - 1 - s;
    k_lstm_step<<<2512, 256, 0, stream>>>(
        xsb + (size_t)t * NC, CH, hb[(s + 1) & 1], (s == 0) ? 0 : HID,
        wihb_p, whhb_p, biasb_p, hb[s & 1], cbuf, jkw + HID,
        scores + (size_t)t * N_NODES, N_NODES, s == 0);
  }

  // ---- JK combine (+BN reduce) + BN apply ----
  hipMemsetAsync(sums, 0, 2048, stream);
  k_jk<<<256, 256, 0, stream>>>(scores, xsb, (float*)d_out, sums);
  k_bnapply<<<(int)(NC / 256), 256, 0, stream>>>((float*)d_out, sums, gamma, beta);
}

// Round 12
// 1498.208 us; speedup vs baseline: 1.0181x; 1.0181x over previous
//
#include <hip/hip_runtime.h>
#include <hip/hip_bf16.h>
#include <math.h>

#define N_NODES 20000
#define N_EDGES 640000
#define CH 256        // HEADS*DIM
#define LAYERS 4
#define HID 512
#define G4 2048       // 4*HID
#define EPS 1e-5f
#define SLOPE 0.2f

typedef __bf16 bf16x8 __attribute__((ext_vector_type(8)));
typedef float  f32x4  __attribute__((ext_vector_type(4)));

// ---------------- helpers ----------------
// async global->LDS, 16B per lane; lds dest = wave-uniform base + lane*16
__device__ __forceinline__ void gload16(const void* g, void* l){
  __builtin_amdgcn_global_load_lds(
      (const __attribute__((address_space(1))) void*)g,
      (__attribute__((address_space(3))) void*)l, 16, 0, 0);
}

// bf16 pair -> float2 (bf16->f32 is a 16-bit shift)
__device__ __forceinline__ float2 ldbf2(const __hip_bfloat16* p){
  unsigned u = *(const unsigned*)p;
  float2 r;
  r.x = __uint_as_float(u << 16);
  r.y = __uint_as_float(u & 0xffff0000u);
  return r;
}

// bijective chunked XCD swizzle (m204): contiguous wgid ranges per XCD
__device__ __forceinline__ int xcd_swz(int orig, int q, int r){
  int xcd = orig & 7, idx = orig >> 3;
  return (xcd < r ? xcd * (q + 1) : r * (q + 1) + (xcd - r) * q) + idx;
}

// LDS granule XOR-swizzle (T2): rows are 64B (4x 16B granules); unswizzled reads
// put 16 lanes (l15) on 2 bank-starts -> 8-way conflict. Involution: LDS(row,g)
// holds global(row, g ^ ((row>>1)&3)); source-side and read-side XOR terms are
// per-lane constants because all row bases are multiples of 16. Bit-exact.

// ---------------- CSR build ----------------
__global__ void k_hist(const int* __restrict__ dst, int* __restrict__ cnt){
  int e = blockIdx.x * 256 + threadIdx.x;
  if (e < N_EDGES) atomicAdd(&cnt[dst[e]], 1);
}

__global__ __launch_bounds__(1024) void k_scan(const int* __restrict__ cnt,
                                               int* __restrict__ indptr,
                                               int* __restrict__ cursor){
  __shared__ int buf[1024];
  __shared__ int carry;
  if (threadIdx.x == 0) carry = 0;
  __syncthreads();
  for (int base = 0; base < N_NODES; base += 1024){
    int i = base + threadIdx.x;
    int v = (i < N_NODES) ? cnt[i] : 0;
    buf[threadIdx.x] = v;
    __syncthreads();
#pragma unroll
    for (int off = 1; off < 1024; off <<= 1){
      int t = (threadIdx.x >= off) ? buf[threadIdx.x - off] : 0;
      __syncthreads();
      buf[threadIdx.x] += t;
      __syncthreads();
    }
    int excl = buf[threadIdx.x] - v;
    if (i < N_NODES){
      indptr[i] = carry + excl;
      cursor[i] = carry + excl;
    }
    __syncthreads();
    if (threadIdx.x == 0) carry += buf[1023];
    __syncthreads();
  }
  if (threadIdx.x == 0) indptr[N_NODES] = carry;
}

// scatter src + edge_attr into dst-sorted order
__global__ void k_scatter(const int* __restrict__ src, const int* __restrict__ dst,
                          const float* __restrict__ ea, int* __restrict__ cursor,
                          int* __restrict__ esrc, float* __restrict__ eea){
  int e = blockIdx.x * 256 + threadIdx.x;
  if (e < N_EDGES){
    int pos = atomicAdd(&cursor[dst[e]], 1);
    esrc[pos] = src[e];
    eea[pos] = ea[e];
  }
}

// ---------------- LSTM weight permute+convert ----------------
// in row r = g*512 + j  ->  out row nr = (j/16)*64 + g*16 + (j%16)
__global__ void k_wperm(const float* __restrict__ W, __hip_bfloat16* __restrict__ Wp,
                        int K){
  int idx = blockIdx.x * 256 + threadIdx.x;
  if (idx >= G4 * K) return;
  int r = idx / K, k = idx - r * K;
  int g = r >> 9, j = r & 511;
  int nr = ((j >> 4) << 6) + (g << 4) + (j & 15);
  Wp[(size_t)nr * K + k] = __float2bfloat16(W[idx]);
}

__global__ void k_bperm(const float* __restrict__ bih, const float* __restrict__ bhh,
                        float* __restrict__ bp){
  int r = blockIdx.x * 256 + threadIdx.x;   // 0..2047
  if (r >= G4) return;
  int g = r >> 9, j = r & 511;
  int nr = ((j >> 4) << 6) + (g << 4) + (j & 15);
  bp[nr] = bih[r] + bhh[r];
}

// GAT weight transpose+convert: Wl,Wr [K=256][N=256] k-major f32 ->
// out [512][256] n-major bf16 (rows 0-255 = Wl^T, 256-511 = Wr^T)
__global__ void k_wtrans(const float* __restrict__ Wl, const float* __restrict__ Wr,
                         __hip_bfloat16* __restrict__ out){
  int idx = blockIdx.x * 256 + threadIdx.x;
  if (idx >= CH * CH) return;
  int n = idx >> 8, k = idx & 255;
  out[(size_t)n * CH + k]        = __float2bfloat16(Wl[(size_t)k * CH + n]);
  out[(size_t)(CH + n) * CH + k] = __float2bfloat16(Wr[(size_t)k * CH + n]);
}

// ---------------- layer-0 transform (K=2): xl -> bf16, xr -> f32 ----------------
__global__ void k_xf0(const float* __restrict__ x, const float* __restrict__ Wl,
                      const float* __restrict__ Wr, __hip_bfloat16* __restrict__ xlb,
                      float* __restrict__ xr){
  int idx = blockIdx.x * 256 + threadIdx.x;
  int n = idx >> 8, cx = idx & 255;
  float x0 = x[n * 2], x1 = x[n * 2 + 1];
  xlb[idx] = __float2bfloat16(fmaf(x0, Wl[cx], x1 * Wl[CH + cx]));
  xr[idx]  = fmaf(x0, Wr[cx], x1 * Wr[CH + cx]);
}

// ---------------- fused GAT transform (MFMA): [xl|xr] = xs_prev * [Wl|Wr] ----------------
// A:[M][256] bf16, B:[512][256] bf16 n-major. cols 0-255 -> xlb bf16, 256-511 -> xr f32.
__global__ __launch_bounds__(256) void k_xform(
    const __hip_bfloat16* __restrict__ A, const __hip_bfloat16* __restrict__ B,
    __hip_bfloat16* __restrict__ xlb, float* __restrict__ xr, int M)
{
  __shared__ __align__(16) unsigned short As[128 * 32];
  __shared__ __align__(16) unsigned short Bs[128 * 32];
  const int wgid = xcd_swz(blockIdx.x, 628 >> 3, 628 & 7);
  const int m0 = (wgid >> 2) * 128, n0 = (wgid & 3) * 128;   // m-major: A-panel reuse
  const int tid = threadIdx.x;
  const int lane = tid & 63, w = tid >> 6;
  const int wr = w >> 1, wc = w & 1;
  const int l15 = lane & 15, l4 = lane >> 4;
  const int srow = lane >> 2;
  const int skk  = (((lane & 3) ^ ((lane >> 3) & 3)) * 8);  // swizzled SOURCE granule
  const int gsw  = (l4 ^ ((l15 >> 1) & 3)) * 8;             // swizzled READ granule

  f32x4 acc[4][4];
#pragma unroll
  for (int i = 0; i < 4; i++)
#pragma unroll
    for (int j = 0; j < 4; j++) acc[i][j] = (f32x4){0.f, 0.f, 0.f, 0.f};

  for (int kt = 0; kt < 8; ++kt){
    int k0 = kt * 32;
#pragma unroll
    for (int i = 0; i < 2; i++){
      int rbase = w * 32 + i * 16;
      int row = rbase + srow;
      gload16(A + (size_t)(m0 + row) * CH + k0 + skk, &As[rbase * 32]);
      gload16(B + (size_t)(n0 + row) * CH + k0 + skk, &Bs[rbase * 32]);
    }
    __syncthreads();
    bf16x8 af[4], bfr[4];
#pragma unroll
    for (int f = 0; f < 4; f++){
      af[f]  = *(const bf16x8*)&As[(wr * 64 + f * 16 + l15) * 32 + gsw];
      bfr[f] = *(const bf16x8*)&Bs[(wc * 64 + f * 16 + l15) * 32 + gsw];
    }
#pragma unroll
    for (int fi = 0; fi < 4; fi++)
#pragma unroll
      for (int fj = 0; fj < 4; fj++)
        acc[fi][fj] = __builtin_amdgcn_mfma_f32_16x16x32_bf16(af[fi], bfr[fj],
                                                              acc[fi][fj], 0, 0, 0);
    __syncthreads();
  }

  // epilogue: D col = lane&15, row = (lane>>4)*4 + reg [m89]; split outputs at col 256
#pragma unroll
  for (int fj = 0; fj < 4; fj++){
    int col = n0 + wc * 64 + fj * 16 + l15;
#pragma unroll
    for (int fi = 0; fi < 4; fi++){
      int rbase = m0 + wr * 64 + fi * 16 + l4 * 4;
#pragma unroll
      for (int r = 0; r < 4; r++){
        int row = rbase + r;
        if (row < M){
          if (col < CH) xlb[(size_t)row * CH + col] = __float2bfloat16(acc[fi][fj][r]);
          else          xr[(size_t)row * CH + (col - CH)] = acc[fi][fj][r];
        }
      }
    }
  }
}

// ---------------- fused LSTM step: gates GEMM + cell + JK partial ----------------
// 1-D grid 2512 with XCD swizzle, m-major (16 y-blocks of a panel share an XCD L2).
// A1:[M][256] bf16 (xs_t), A2:[M][512] bf16 (h_in, K2=0 at t=0)
// B1/B2: PERMUTED weights [2048][K] bf16; biasp: permuted bih+bhh [2048] f32
// h_out MUST differ from h_in (A2 rows are read by all y-blocks of the panel).
__global__ __launch_bounds__(256) void k_lstm_step(
    const __hip_bfloat16* __restrict__ A1, int K1,
    const __hip_bfloat16* __restrict__ A2, int K2,
    const __hip_bfloat16* __restrict__ B1, const __hip_bfloat16* __restrict__ B2,
    const float* __restrict__ biasp, __hip_bfloat16* __restrict__ h_out,
    float* __restrict__ c, const float* __restrict__ jkw,
    float* __restrict__ score, int M, int first)
{
  __shared__ __align__(16) unsigned short As[128 * 32];
  __shared__ __align__(16) unsigned short Bs[128 * 32];
  const int wgid = xcd_swz(blockIdx.x, 2512 >> 3, 2512 & 7);
  const int m0 = (wgid >> 4) * 128;
  const int yb = wgid & 15;
  const int n0 = yb * 128;
  const int tid = threadIdx.x;
  const int lane = tid & 63, w = tid >> 6;
  const int wr = w >> 1, wc = w & 1;
  const int l15 = lane & 15, l4 = lane >> 4;
  const int srow = lane >> 2;
  const int skk  = (((lane & 3) ^ ((lane >> 3) & 3)) * 8);  // swizzled SOURCE granule
  const int gsw  = (l4 ^ ((l15 >> 1) & 3)) * 8;             // swizzled READ granule

  f32x4 acc[4][4];
#pragma unroll
  for (int i = 0; i < 4; i++)
#pragma unroll
    for (int j = 0; j < 4; j++) acc[i][j] = (f32x4){0.f, 0.f, 0.f, 0.f};

  const int nt1 = K1 / 32, nt2 = K2 / 32;

  for (int kt = 0; kt < nt1 + nt2; ++kt){
    const __hip_bfloat16* Ab; const __hip_bfloat16* Bb; int K, k0;
    if (kt < nt1){ Ab = A1; Bb = B1; K = K1; k0 = kt * 32; }
    else         { Ab = A2; Bb = B2; K = K2; k0 = (kt - nt1) * 32; }
#pragma unroll
    for (int i = 0; i < 2; i++){
      int rbase = w * 32 + i * 16;
      int row = rbase + srow;
      gload16(Ab + (size_t)(m0 + row) * K + k0 + skk, &As[rbase * 32]);
      gload16(Bb + (size_t)(n0 + row) * K + k0 + skk, &Bs[rbase * 32]);
    }
    __syncthreads();
    bf16x8 af[4], bfr[4];
#pragma unroll
    for (int f = 0; f < 4; f++){
      af[f]  = *(const bf16x8*)&As[(wr * 64 + f * 16 + l15) * 32 + gsw];
      bfr[f] = *(const bf16x8*)&Bs[(wc * 64 + f * 16 + l15) * 32 + gsw];
    }
#pragma unroll
    for (int fi = 0; fi < 4; fi++)
#pragma unroll
      for (int fj = 0; fj < 4; fj++)
        acc[fi][fj] = __builtin_amdgcn_mfma_f32_16x16x32_bf16(af[fi], bfr[fj],
                                                              acc[fi][fj], 0, 0, 0);
    __syncthreads();
  }

  // ---- fused cell epilogue ----
  const int block64 = yb * 2 + wc;             // 0..31
  const int j = block64 * 16 + l15;            // hidden channel 0..511
  const float bi0 = biasp[block64 * 64 + l15];
  const float bi1 = biasp[block64 * 64 + 16 + l15];
  const float bi2 = biasp[block64 * 64 + 32 + l15];
  const float bi3 = biasp[block64 * 64 + 48 + l15];
  const float jw  = jkw[j];
#pragma unroll
  for (int fi = 0; fi < 4; fi++){
#pragma unroll
    for (int r = 0; r < 4; r++){
      int node = m0 + wr * 64 + fi * 16 + l4 * 4 + r;
      float p = 0.f;
      if (node < M){
        float gi = acc[fi][0][r] + bi0;
        float gf = acc[fi][1][r] + bi1;
        float gg = acc[fi][2][r] + bi2;
        float go = acc[fi][3][r] + bi3;
        size_t hb = (size_t)node * HID + j;
        float cv = first ? 0.f : c[hb];
        float iv = 1.f / (1.f + __expf(-gi));
        float fv = 1.f / (1.f + __expf(-gf));
        float ov = 1.f / (1.f + __expf(-go));
        float cn = fv * cv + iv * tanhf(gg);
        float hn = ov * tanhf(cn);
        c[hb] = cn;
        h_out[hb] = __float2bfloat16(hn);
        p = hn * jw;
      }
      p += __shfl_xor(p, 1, 64); p += __shfl_xor(p, 2, 64);
      p += __shfl_xor(p, 4, 64); p += __shfl_xor(p, 8, 64);
      if (l15 == 0 && node < M) atomicAdd(&score[node], p);
    }
  }
}

// ---------------- fused GAT message pass (bf16 gathers, 4-way unrolled) ----------------
__global__ __launch_bounds__(128) void k_gat(
    const int* __restrict__ indptr, const int* __restrict__ esrc,
    const float* __restrict__ eea, const __hip_bfloat16* __restrict__ xlb,
    const float* __restrict__ xr, const float* __restrict__ We,
    const float* __restrict__ att, const float* __restrict__ bias,
    __hip_bfloat16* __restrict__ xsb)
{
  const int n = blockIdx.x;
  const int t = threadIdx.x;              // ch pair (2t, 2t+1); head = t>>5
  const int c0 = 2 * t;
  const int s0 = indptr[n], s1 = indptr[n + 1];
  const float2 xr_t = *(const float2*)&xr[(size_t)n * CH + c0];
  const float2 We_t = *(const float2*)&We[c0];
  const float2 at_t = *(const float2*)&att[c0];
  float m = -1e30f, l = 0.f;
  float2 acc = make_float2(0.f, 0.f);

  int i = s0;
  for (; i + 3 < s1; i += 4){             // 4-way unroll: 4 gathers in flight
    int   sA = esrc[i],     sB = esrc[i + 1];
    int   sC = esrc[i + 2], sD = esrc[i + 3];
    float aA = eea[i],      aB = eea[i + 1];
    float aC = eea[i + 2],  aD = eea[i + 3];
    float2 xvA = ldbf2(xlb + (size_t)sA * CH + c0);
    float2 xvB = ldbf2(xlb + (size_t)sB * CH + c0);
    float2 xvC = ldbf2(xlb + (size_t)sC * CH + c0);
    float2 xvD = ldbf2(xlb + (size_t)sD * CH + c0);
    // pre-activation + leaky-relu + att-dot (independent per edge)
    float vxA = xvA.x + xr_t.x + aA * We_t.x, vyA = xvA.y + xr_t.y + aA * We_t.y;
    float vxB = xvB.x + xr_t.x + aB * We_t.x, vyB = xvB.y + xr_t.y + aB * We_t.y;
    float vxC = xvC.x + xr_t.x + aC * We_t.x, vyC = xvC.y + xr_t.y + aC * We_t.y;
    float vxD = xvD.x + xr_t.x + aD * We_t.x, vyD = xvD.y + xr_t.y + aD * We_t.y;
    vxA = vxA > 0.f ? vxA : SLOPE * vxA;  vyA = vyA > 0.f ? vyA : SLOPE * vyA;
    vxB = vxB > 0.f ? vxB : SLOPE * vxB;  vyB = vyB > 0.f ? vyB : SLOPE * vyB;
    vxC = vxC > 0.f ? vxC : SLOPE * vxC;  vyC = vyC > 0.f ? vyC : SLOPE * vyC;
    vxD = vxD > 0.f ? vxD : SLOPE * vxD;  vyD = vyD > 0.f ? vyD : SLOPE * vyD;
    float pA = vxA * at_t.x + vyA * at_t.y;
    float pB = vxB * at_t.x + vyB * at_t.y;
    float pC = vxC * at_t.x + vyC * at_t.y;
    float pD = vxD * at_t.x + vyD * at_t.y;
    // 4 independent 32-lane reduce chains (compiler interleaves)
#pragma unroll
    for (int off = 16; off; off >>= 1){
      pA += __shfl_xor(pA, off, 64);
      pB += __shfl_xor(pB, off, 64);
      pC += __shfl_xor(pC, off, 64);
      pD += __shfl_xor(pD, off, 64);
    }
    // sequential online-softmax updates (same FP order as 1-at-a-time)
    float mn = fmaxf(m, pA);
    float sc = __expf(m - mn), wE = __expf(pA - mn);
    l = l * sc + wE;
    acc.x = acc.x * sc + wE * xvA.x;  acc.y = acc.y * sc + wE * xvA.y;
    m = mn;
    mn = fmaxf(m, pB);
    sc = __expf(m - mn); wE = __expf(pB - mn);
    l = l * sc + wE;
    acc.x = acc.x * sc + wE * xvB.x;  acc.y = acc.y * sc + wE * xvB.y;
    m = mn;
    mn = fmaxf(m, pC);
    sc = __expf(m - mn); wE = __expf(pC - mn);
    l = l * sc + wE;
    acc.x = acc.x * sc + wE * xvC.x;  acc.y = acc.y * sc + wE * xvC.y;
    m = mn;
    mn = fmaxf(m, pD);
    sc = __expf(m - mn); wE = __expf(pD - mn);
    l = l * sc + wE;
    acc.x = acc.x * sc + wE * xvD.x;  acc.y = acc.y * sc + wE * xvD.y;
    m = mn;
  }
  for (; i < s1; ++i){                    // remainder (<=3 edges)
    int   sA = esrc[i];
    float aA = eea[i];
    float2 xvA = ldbf2(xlb + (size_t)sA * CH + c0);
    float vx = xvA.x + xr_t.x + aA * We_t.x;
    float vy = xvA.y + xr_t.y + aA * We_t.y;
    vx = vx > 0.f ? vx : SLOPE * vx;
    vy = vy > 0.f ? vy : SLOPE * vy;
    float pl = vx * at_t.x + vy * at_t.y;
#pragma unroll
    for (int off = 16; off; off >>= 1) pl += __shfl_xor(pl, off, 64);
    float mn = fmaxf(m, pl);
    float sc = __expf(m - mn), wA = __expf(pl - mn);
    l = l * sc + wA;
    acc.x = acc.x * sc + wA * xvA.x;
    acc.y = acc.y * sc + wA * xvA.y;
    m = mn;
  }
  float invl = (l > 0.f) ? 1.f / l : 0.f;
  float2 bia = *(const float2*)&bias[c0];
  float ox = acc.x * invl + bia.x;
  float oy = acc.y * invl + bia.y;
  ox = ox > 0.f ? ox : 0.f;
  oy = oy > 0.f ? oy : 0.f;
  ushort2 hp;
  hp.x = __bfloat16_as_ushort(__float2bfloat16(ox));
  hp.y = __bfloat16_as_ushort(__float2bfloat16(oy));
  *(ushort2*)&xsb[(size_t)n * CH + c0] = hp;
}

// ---------------- JK softmax combine + BN reduction (fused) ----------------
__global__ __launch_bounds__(256) void k_jk(const float* __restrict__ scores,
                                            const __hip_bfloat16* __restrict__ xsb,
                                            float* __restrict__ out,
                                            float* __restrict__ sums)
{
  const int cx = threadIdx.x;
  const size_t NC = (size_t)N_NODES * CH;
  float s = 0.f, s2 = 0.f;
  for (int n = blockIdx.x; n < N_NODES; n += gridDim.x){
    float s0 = scores[n], s1 = scores[N_NODES + n];
    float sc2 = scores[2 * N_NODES + n], s3 = scores[3 * N_NODES + n];
    float mx = fmaxf(fmaxf(s0, s1), fmaxf(sc2, s3));
    float e0 = __expf(s0 - mx), e1 = __expf(s1 - mx);
    float e2 = __expf(sc2 - mx), e3 = __expf(s3 - mx);
    float inv = 1.f / (e0 + e1 + e2 + e3);
    size_t idx = (size_t)n * CH + cx;
    float v = e0 * __bfloat162float(xsb[idx]) + e1 * __bfloat162float(xsb[NC + idx]) +
              e2 * __bfloat162float(xsb[2 * NC + idx]) +
              e3 * __bfloat162float(xsb[3 * NC + idx]);
    v *= inv;
    out[idx] = v;
    s += v;
    s2 = fmaf(v, v, s2);
  }
  atomicAdd(&sums[cx], s);
  atomicAdd(&sums[CH + cx], s2);
}

__global__ __launch_bounds__(256) void k_bnapply(float* __restrict__ out,
                                                 const float* __restrict__ sums,
                                                 const float* __restrict__ gamma,
                                                 const float* __restrict__ beta)
{
  int idx = blockIdx.x * 256 + threadIdx.x;
  int cx = idx & 255;
  const float invN = 1.f / (float)N_NODES;
  float mean = sums[cx] * invN;
  float var = sums[CH + cx] * invN - mean * mean;
  out[idx] = (out[idx] - mean) * rsqrtf(var + EPS) * gamma[cx] + beta[cx];
}

// ---------------- host ----------------
extern "C" void kernel_launch(void* const* d_in, const int* in_sizes, int n_in,
                              void* d_out, int out_size, void* d_ws, size_t ws_size,
                              hipStream_t stream)
{
  const float* x     = (const float*)d_in[0];
  const int*   eidx  = (const int*)d_in[1];
  const int*   srcp  = eidx;
  const int*   dstp  = eidx + N_EDGES;
  const float* ea    = (const float*)d_in[2];
  const float* Wl0   = (const float*)d_in[3];
  const float* Wr0   = (const float*)d_in[4];
  const float* We0   = (const float*)d_in[5];
  const float* att0  = (const float*)d_in[6];
  const float* b0    = (const float*)d_in[7];
  const float* WlR   = (const float*)d_in[8];
  const float* WrR   = (const float*)d_in[9];
  const float* WeR   = (const float*)d_in[10];
  const float* attR  = (const float*)d_in[11];
  const float* bR    = (const float*)d_in[12];
  const float* Wih_f = (const float*)d_in[13];
  const float* Whh_f = (const float*)d_in[14];
  const float* bih_f = (const float*)d_in[15];
  const float* bhh_f = (const float*)d_in[16];
  const float* Wih_b = (const float*)d_in[17];
  const float* Whh_b = (const float*)d_in[18];
  const float* bih_b = (const float*)d_in[19];
  const float* bhh_b = (const float*)d_in[20];
  const float* jkw   = (const float*)d_in[21];
  const float* gamma = (const float*)d_in[23];
  const float* beta  = (const float*)d_in[24];

  // ---------- byte-precise workspace layout ----------
  char* base = (char*)d_ws;
  const size_t NC   = (size_t)N_NODES * CH;          // 5,120,000 elems
  const size_t NH   = (size_t)N_NODES * HID;         // 10,240,000 elems
  size_t off = 0;
  __hip_bfloat16* wihf_p = (__hip_bfloat16*)(base + off); off += (size_t)G4 * CH * 2;
  __hip_bfloat16* whhf_p = (__hip_bfloat16*)(base + off); off += (size_t)G4 * HID * 2;
  __hip_bfloat16* wihb_p = (__hip_bfloat16*)(base + off); off += (size_t)G4 * CH * 2;
  __hip_bfloat16* whhb_p = (__hip_bfloat16*)(base + off); off += (size_t)G4 * HID * 2;
  float* biasf_p = (float*)(base + off); off += G4 * 4;
  float* biasb_p = (float*)(base + off); off += G4 * 4;
  float* scores  = (float*)(base + off); off += (size_t)LAYERS * N_NODES * 4;
  float* sums    = (float*)(base + off); off += 2048;
  __hip_bfloat16* xsb = (__hip_bfloat16*)(base + off); off += LAYERS * NC * 2;
  const size_t R = off;                              // shared region base (~47.6 MB)
  // GAT view of R (all dead before LSTM phase)
  float* xr = (float*)(base + R);                    // [N][CH] f32 target transform
  __hip_bfloat16* xlb = (__hip_bfloat16*)(xr + NC);  // [N][CH] bf16 source transform
  int*   indptr = (int*)(xlb + NC);                  // N+1
  int*   cursor = indptr + (N_NODES + 1);            // N
  int*   esrc   = cursor + N_NODES;                  // E (dst-sorted src)
  float* eea    = (float*)(esrc + N_EDGES);          // E (dst-sorted edge_attr)
  __hip_bfloat16* wgat_p = (__hip_bfloat16*)(eea + N_EDGES);  // [3][512][256] bf16
  const size_t gat_end = R + NC * 4 + NC * 2
                       + (2 * (size_t)N_NODES + 1 + 2 * (size_t)N_EDGES) * 4
                       + 3 * (size_t)2 * CH * CH * 2;
  // LSTM view of R: h0, h1, c ordered so tail OOB reads stay interior
  __hip_bfloat16* hbuf0 = (__hip_bfloat16*)(base + R);            // [N][HID] bf16
  __hip_bfloat16* hbuf1 = (__hip_bfloat16*)(base + R + NH * 2);   // [N][HID] bf16
  float* cbuf  = (float*)(base + R + NH * 4);                     // [N][HID] f32
  const size_t lstm_end = R + NH * 4 + NH * 4;

  if (gat_end > ws_size || lstm_end > ws_size) return;  // leave output poisoned

  // ---- CSR by dst (src/ea stored dst-sorted) ----
  hipMemsetAsync(cursor, 0, N_NODES * sizeof(int), stream);
  k_hist<<<(N_EDGES + 255) / 256, 256, 0, stream>>>(dstp, cursor);
  k_scan<<<1, 1024, 0, stream>>>(cursor, indptr, cursor);
  k_scatter<<<(N_EDGES + 255) / 256, 256, 0, stream>>>(srcp, dstp, ea, cursor,
                                                       esrc, eea);

  // ---- weight prep ----
  k_wperm<<<(G4 * CH + 255) / 256, 256, 0, stream>>>(Wih_f, wihf_p, CH);
  k_wperm<<<(G4 * HID + 255) / 256, 256, 0, stream>>>(Whh_f, whhf_p, HID);
  k_wperm<<<(G4 * CH + 255) / 256, 256, 0, stream>>>(Wih_b, wihb_p, CH);
  k_wperm<<<(G4 * HID + 255) / 256, 256, 0, stream>>>(Whh_b, whhb_p, HID);
  k_bperm<<<(G4 + 255) / 256, 256, 0, stream>>>(bih_f, bhh_f, biasf_p);
  k_bperm<<<(G4 + 255) / 256, 256, 0, stream>>>(bih_b, bhh_b, biasb_p);
  for (int l = 0; l < LAYERS - 1; ++l)
    k_wtrans<<<(CH * CH + 255) / 256, 256, 0, stream>>>(
        WlR + (size_t)l * CH * CH, WrR + (size_t)l * CH * CH,
        wgat_p + (size_t)l * 2 * CH * CH);

  // ---- GATv2 layers (MFMA transforms from bf16 xs; fused message pass) ----
  for (int l = 0; l < LAYERS; ++l){
    if (l == 0){
      k_xf0<<<(int)(NC / 256), 256, 0, stream>>>(x, Wl0, Wr0, xlb, xr);
    } else {
      k_xform<<<628, 256, 0, stream>>>(
          xsb + (size_t)(l - 1) * NC, wgat_p + (size_t)(l - 1) * 2 * CH * CH,
          xlb, xr, N_NODES);
    }
    const float* We  = (l == 0) ? We0  : WeR  + (size_t)(l - 1) * CH;
    const float* att = (l == 0) ? att0 : attR + (size_t)(l - 1) * CH;
    const float* bia = (l == 0) ? b0   : bR   + (size_t)(l - 1) * CH;
    k_gat<<<N_NODES, 128, 0, stream>>>(indptr, esrc, eea, xlb, xr, We, att, bia,
                                       xsb + (size_t)l * NC);
  }

  // ---- LSTM (scores accumulated atomically; zero once) ----
  __hip_bfloat16* hb[2] = {hbuf0, hbuf1};
  hipMemsetAsync(scores, 0, (size_t)LAYERS * N_NODES * 4, stream);
  for (int t = 0; t < LAYERS; t++){
    k_lstm_step<<<2512, 256, 0, stream>>>(
        xsb + (size_t)t * NC, CH, hb[(t + 1) & 1], (t == 0) ? 0 : HID,
        wihf_p, whhf_p, biasf_p, hb[t & 1], cbuf, jkw,
        scores + (size_t)t * N_NODES, N_NODES, t == 0);
  }
  for (int s = 0; s < LAYERS; s++){
    int t = LAYERS - 1 - s;
    k_lstm_step<<<2512, 256, 0, stream>>>(
        xsb + (size_t)t * NC, CH, hb[(s + 1) & 1], (s == 0) ? 0 : HID,
        wihb_p, whhb_p, biasb_p, hb[s & 1], cbuf, jkw + HID,
        scores + (size_t)t * N_NODES, N_NODES, s == 0);
  }

  // ---- JK combine (+BN reduce) + BN apply ----
  hipMemsetAsync(sums, 0, 2048, stream);
  k_jk<<<256, 256, 0, stream>>>(scores, xsb, (float*)d_out, sums);
  k_bnapply<<<(int)(NC / 256), 256, 0, stream>>>((float*)d_out, sums, gamma, beta);
}